// Round 6
// baseline (323.837 us; speedup 1.0000x reference)
//
#include <hip/hip_runtime.h>

// SAGEDense: h=relu(x@W1+b1); hn=mean_agg(h,src,dst); h2=relu(h@Ws+hn@Wn+b); out=relu(h2@W2+b2)
// GEMMs: M=100000, N=K=128, bf16 MFMA fp32-accum.
// Aggregation: CSR (count / multiblock scan / XCD-partitioned fill with NT edge
// reads) + per-node register-accumulating gather.

typedef __bf16 bf16x8 __attribute__((ext_vector_type(8)));
typedef float f32x4 __attribute__((ext_vector_type(4)));

#define D 128

__device__ __forceinline__ unsigned short f2bf(float f){
  unsigned int u = __float_as_uint(f);
  u += 0x7FFF + ((u >> 16) & 1);           // RNE
  return (unsigned short)(u >> 16);
}
__device__ __forceinline__ float bf2f(unsigned int us){
  return __uint_as_float(us << 16);
}

// All 4 weights in one launch: 512 blocks = 4 x 128 k-rows; [k][n] fp32 -> [n][k] bf16
__global__ void prep_w_all(const float* __restrict__ Wa, const float* __restrict__ Wb,
                           const float* __restrict__ Wc, const float* __restrict__ Wd,
                           unsigned short* __restrict__ Ta, unsigned short* __restrict__ Tb,
                           unsigned short* __restrict__ Tc, unsigned short* __restrict__ Td){
  int which = blockIdx.x >> 7;
  int k = blockIdx.x & 127;
  int n = threadIdx.x;
  const float* W = (which == 0) ? Wa : (which == 1) ? Wb : (which == 2) ? Wc : Wd;
  unsigned short* T = (which == 0) ? Ta : (which == 1) ? Tb : (which == 2) ? Tc : Td;
  T[n * D + k] = f2bf(W[k * D + n]);
}

// ---------------- CSR build ----------------
__global__ void count_deg(const int* __restrict__ edst, int* __restrict__ cnt, int E){
  int e = blockIdx.x * blockDim.x + threadIdx.x;
  if (e < E) atomicAdd(&cnt[__builtin_nontemporal_load(edst + e)], 1);
}

// Multi-block exclusive scan of cnt[0..N) -> rowptr[0..N] (and fillpos copy).
__global__ void scan_a(const int* __restrict__ in, int* __restrict__ bsum, int N){
  __shared__ int red[256];
  int t = threadIdx.x;
  int i0 = blockIdx.x * 512 + t * 2;
  int s = 0;
  if (i0 < N)     s += in[i0];
  if (i0 + 1 < N) s += in[i0 + 1];
  red[t] = s;
  __syncthreads();
  #pragma unroll
  for (int d = 128; d > 0; d >>= 1){
    if (t < d) red[t] += red[t + d];
    __syncthreads();
  }
  if (t == 0) bsum[blockIdx.x] = red[0];
}

__global__ void scan_b(const int* __restrict__ bsum, int* __restrict__ boff, int nb){
  __shared__ int buf[256];
  int t = threadIdx.x;
  buf[t] = (t < nb) ? bsum[t] : 0;
  __syncthreads();
  #pragma unroll
  for (int d = 1; d < 256; d <<= 1){
    int v = (t >= d) ? buf[t - d] : 0;
    __syncthreads();
    buf[t] += v;
    __syncthreads();
  }
  if (t < nb) boff[t] = (t == 0) ? 0 : buf[t - 1];
}

__global__ void scan_c(const int* __restrict__ in, const int* __restrict__ boff,
                       int* __restrict__ rowptr, int* __restrict__ fillpos, int N){
  __shared__ int buf[256];
  int t = threadIdx.x;
  int i0 = blockIdx.x * 512 + t * 2;
  int c0 = (i0 < N)     ? in[i0]     : 0;
  int c1 = (i0 + 1 < N) ? in[i0 + 1] : 0;
  buf[t] = c0 + c1;
  __syncthreads();
  #pragma unroll
  for (int d = 1; d < 256; d <<= 1){
    int v = (t >= d) ? buf[t - d] : 0;
    __syncthreads();
    buf[t] += v;
    __syncthreads();
  }
  int excl = ((t == 0) ? 0 : buf[t - 1]) + boff[blockIdx.x];
  if (i0 < N)    { rowptr[i0]     = excl;      fillpos[i0]     = excl; }
  if (i0 + 1 < N){ rowptr[i0 + 1] = excl + c0; fillpos[i0 + 1] = excl + c0; }
  if (i0 + 1 == N - 1) rowptr[N] = excl + c0 + c1;
  if (i0 == N - 1)     rowptr[N] = excl + c0;
}

// XCD-partitioned fill: blockIdx%8 selects a dst-range (pinned to one XCD by
// round-robin dispatch) -> single-writer 800KB adj frontier per L2.
// NT loads keep the 8x streamed edge arrays from evicting the dirty frontier,
// so partial-line writes merge in L2 before writeback.
__global__ void fill_adj_xcd(const int* __restrict__ esrc, const int* __restrict__ edst,
                             int* __restrict__ fillpos, int* __restrict__ adj,
                             int E, int M){
  const int xcd = blockIdx.x & 7;
  const int chunk = blockIdx.x >> 3;
  const int lo = (int)(((long long)M * xcd) >> 3);
  const int hi = (int)(((long long)M * (xcd + 1)) >> 3);
  const int base = chunk * 2048;
  const int lim = min(base + 2048, E);
  for (int i = base + threadIdx.x; i < lim; i += 256){
    int d = __builtin_nontemporal_load(edst + i);
    if (d >= lo && d < hi){
      int s = __builtin_nontemporal_load(esrc + i);
      int p = atomicAdd(&fillpos[d], 1);
      adj[p] = s;
    }
  }
}

// one wave per dst node; lane owns 4 bytes (2 bf16 dims); fp32 register accumulate
__global__ void gather_mean(const unsigned short* __restrict__ h,
                            const int* __restrict__ rowptr,
                            const int* __restrict__ adj,
                            unsigned short* __restrict__ hn, int N){
  int wid = (blockIdx.x * blockDim.x + threadIdx.x) >> 6;
  int lane = threadIdx.x & 63;
  if (wid >= N) return;
  int beg = rowptr[wid], end = rowptr[wid + 1];
  float a0 = 0.f, a1 = 0.f;
  int i = beg;
  for (; i + 3 < end; i += 4){
    int s0 = adj[i], s1 = adj[i + 1], s2 = adj[i + 2], s3 = adj[i + 3];
    unsigned p0 = *(const unsigned*)(h + (size_t)s0 * D + lane * 2);
    unsigned p1 = *(const unsigned*)(h + (size_t)s1 * D + lane * 2);
    unsigned p2 = *(const unsigned*)(h + (size_t)s2 * D + lane * 2);
    unsigned p3 = *(const unsigned*)(h + (size_t)s3 * D + lane * 2);
    a0 += bf2f(p0 & 0xffffu); a1 += bf2f(p0 >> 16);
    a0 += bf2f(p1 & 0xffffu); a1 += bf2f(p1 >> 16);
    a0 += bf2f(p2 & 0xffffu); a1 += bf2f(p2 >> 16);
    a0 += bf2f(p3 & 0xffffu); a1 += bf2f(p3 >> 16);
  }
  for (; i < end; i++){
    int s0 = adj[i];
    unsigned p0 = *(const unsigned*)(h + (size_t)s0 * D + lane * 2);
    a0 += bf2f(p0 & 0xffffu); a1 += bf2f(p0 >> 16);
  }
  float inv = 1.0f / fmaxf((float)(end - beg), 1.0f);
  unsigned o = (unsigned)f2bf(a0 * inv) | ((unsigned)f2bf(a1 * inv) << 16);
  *(unsigned*)(hn + (size_t)wid * D + lane * 2) = o;
}

// ---------------- GEMM ----------------
// MODE 0: A1 fp32 -> bf16 out (x@W1)
// MODE 1: A1 bf16 @ Wt1 + A2 bf16 @ Wt2 -> bf16 out (SAGE combine)
// MODE 2: A1 bf16 -> fp32 out (final)
template<int MODE>
__launch_bounds__(256, 2)
__global__ void gemm_k(const void* __restrict__ A1,
                       const unsigned short* __restrict__ Wt1,
                       const void* __restrict__ A2,
                       const unsigned short* __restrict__ Wt2,
                       const float* __restrict__ bias,
                       void* __restrict__ out,
                       int M)
{
  __shared__ unsigned short As[128 * 128];  // [row][k] bf16, XOR-swizzled
  __shared__ unsigned short Bs[128 * 128];  // [n][k]  bf16, XOR-swizzled

  const int t = threadIdx.x;
  const int lane = t & 63;
  const int wave = t >> 6;
  const int rowBase = blockIdx.x * 128;

  f32x4 zero = {0.f, 0.f, 0.f, 0.f};
  f32x4 acc[4][4];
  #pragma unroll
  for (int i = 0; i < 4; i++)
    #pragma unroll
    for (int j = 0; j < 4; j++) acc[i][j] = zero;

  auto stage_bf16 = [&](const unsigned short* A){
    #pragma unroll
    for (int i = 0; i < 8; i++){
      int idx = t + i * 256;
      int row = idx >> 4;
      int inb = (idx & 15) << 4;
      int g = rowBase + row; if (g >= M) g = M - 1;
      uint4 v = *(const uint4*)((const char*)A + (size_t)g * 256 + inb);
      *(uint4*)((char*)As + row * 256 + (inb ^ ((row & 7) << 4))) = v;
    }
  };
  auto stage_f32 = [&](const float* A){
    #pragma unroll
    for (int i = 0; i < 8; i++){
      int idx = t + i * 256;
      int row = idx >> 4;
      int inb = (idx & 15) << 4;
      int g = rowBase + row; if (g >= M) g = M - 1;
      const float* src = A + (size_t)g * D + (inb >> 1);
      float4 v0 = *(const float4*)src;
      float4 v1 = *(const float4*)(src + 4);
      uint4 o;
      o.x = (unsigned)f2bf(v0.x) | ((unsigned)f2bf(v0.y) << 16);
      o.y = (unsigned)f2bf(v0.z) | ((unsigned)f2bf(v0.w) << 16);
      o.z = (unsigned)f2bf(v1.x) | ((unsigned)f2bf(v1.y) << 16);
      o.w = (unsigned)f2bf(v1.z) | ((unsigned)f2bf(v1.w) << 16);
      *(uint4*)((char*)As + row * 256 + (inb ^ ((row & 7) << 4))) = o;
    }
  };
  auto stage_w = [&](const unsigned short* W){
    #pragma unroll
    for (int i = 0; i < 8; i++){
      int idx = t + i * 256;
      int row = idx >> 4;
      int inb = (idx & 15) << 4;
      uint4 v = *(const uint4*)((const char*)W + row * 256 + inb);
      *(uint4*)((char*)Bs + row * 256 + (inb ^ ((row & 7) << 4))) = v;
    }
  };

  const int wr = (wave >> 1) * 64;
  const int wc = (wave & 1) * 64;
  const int fr = lane & 15;
  const int kg = lane >> 4;

  auto ld_frag = [&](const unsigned short* S, int row, int kb) -> bf16x8 {
    uint4 v = *(const uint4*)((const char*)S + row * 256 + (kb ^ ((row & 7) << 4)));
    return __builtin_bit_cast(bf16x8, v);
  };
  auto mma_pass = [&](){
    #pragma unroll
    for (int ks = 0; ks < 4; ks++){
      int kb = ks * 64 + kg * 16;
      bf16x8 a[4], b[4];
      #pragma unroll
      for (int mi = 0; mi < 4; mi++) a[mi] = ld_frag(As, wr + mi * 16 + fr, kb);
      #pragma unroll
      for (int ni = 0; ni < 4; ni++) b[ni] = ld_frag(Bs, wc + ni * 16 + fr, kb);
      #pragma unroll
      for (int mi = 0; mi < 4; mi++)
        #pragma unroll
        for (int ni = 0; ni < 4; ni++)
          acc[mi][ni] = __builtin_amdgcn_mfma_f32_16x16x32_bf16(a[mi], b[ni], acc[mi][ni], 0, 0, 0);
    }
  };

  if (MODE == 0){
    stage_f32((const float*)A1);
    stage_w(Wt1);
    __syncthreads();
    mma_pass();
  } else if (MODE == 1){
    stage_bf16((const unsigned short*)A1);
    stage_w(Wt1);
    __syncthreads();
    mma_pass();
    __syncthreads();
    stage_bf16((const unsigned short*)A2);
    stage_w(Wt2);
    __syncthreads();
    mma_pass();
  } else {
    stage_bf16((const unsigned short*)A1);
    stage_w(Wt1);
    __syncthreads();
    mma_pass();
  }

  // epilogue: bias + relu. C/D layout: col=lane&15, row=(lane>>4)*4+reg
  #pragma unroll
  for (int ni = 0; ni < 4; ni++){
    int col = wc + ni * 16 + fr;
    float bv = bias[col];
    #pragma unroll
    for (int mi = 0; mi < 4; mi++){
      #pragma unroll
      for (int j = 0; j < 4; j++){
        int row = rowBase + wr + mi * 16 + kg * 4 + j;
        if (row < M){
          float v = fmaxf(acc[mi][ni][j] + bv, 0.0f);
          if (MODE == 2) ((float*)out)[(size_t)row * D + col] = v;
          else ((unsigned short*)out)[(size_t)row * D + col] = f2bf(v);
        }
      }
    }
  }
}

extern "C" void kernel_launch(void* const* d_in, const int* in_sizes, int n_in,
                              void* d_out, int out_size, void* d_ws, size_t ws_size,
                              hipStream_t stream)
{
  const float* x     = (const float*)d_in[0];
  const int*   esrc  = (const int*)d_in[1];
  const int*   edst  = (const int*)d_in[2];
  const float* W1    = (const float*)d_in[3];
  const float* b1    = (const float*)d_in[4];
  const float* Wself = (const float*)d_in[5];
  const float* Wneigh= (const float*)d_in[6];
  const float* bsage = (const float*)d_in[7];
  const float* W2    = (const float*)d_in[8];
  const float* b2    = (const float*)d_in[9];

  const int M = in_sizes[0] / D;   // 100000
  const int E = in_sizes[1];       // 1600000

  // ---- workspace layout ----
  char* ws = (char*)d_ws;
  unsigned short* W1t = (unsigned short*)(ws);
  unsigned short* Wst = (unsigned short*)(ws + 32768);
  unsigned short* Wnt = (unsigned short*)(ws + 65536);
  unsigned short* W2t = (unsigned short*)(ws + 98304);
  size_t hbytes = (size_t)M * D * 2;            // 25.6 MB each
  unsigned short* h   = (unsigned short*)(ws + 131072);
  unsigned short* h2  = (unsigned short*)(ws + 131072 + hbytes);
  unsigned short* hn  = (unsigned short*)(ws + 131072 + 2 * hbytes);
  char* p = ws + 131072 + 3 * hbytes;
  int* cnt     = (int*)p;                 p += (size_t)M * 4;
  int* fillpos = (int*)p;                 p += (size_t)M * 4;
  int* rowptr  = (int*)p;                 p += (size_t)(M + 4) * 4;
  int* bsum    = (int*)p;                 p += 1024;
  int* boff    = (int*)p;                 p += 1024;
  int* adj     = (int*)p;                 // E * 4 = 6.4 MB

  const int nbScan = (M + 511) / 512;     // 196 <= 256

  prep_w_all<<<4 * D, D, 0, stream>>>(W1, Wself, Wneigh, W2, W1t, Wst, Wnt, W2t);

  hipMemsetAsync(cnt, 0, (size_t)M * 4, stream);

  int nblk = (M + 127) / 128;

  // h = relu(x @ W1 + b1)
  gemm_k<0><<<nblk, 256, 0, stream>>>(x, W1t, nullptr, nullptr, b1, h, M);

  // CSR build
  count_deg<<<(E + 255) / 256, 256, 0, stream>>>(edst, cnt, E);
  scan_a<<<nbScan, 256, 0, stream>>>(cnt, bsum, M);
  scan_b<<<1, 256, 0, stream>>>(bsum, boff, nbScan);
  scan_c<<<nbScan, 256, 0, stream>>>(cnt, boff, rowptr, fillpos, M);
  {
    int chunks = (E + 2047) / 2048;
    fill_adj_xcd<<<8 * chunks, 256, 0, stream>>>(esrc, edst, fillpos, adj, E, M);
  }

  // hn = mean over neighbors (bf16)
  gather_mean<<<(M * 64 + 255) / 256, 256, 0, stream>>>(h, rowptr, adj, hn, M);

  // h2 = relu(h @ W_self + hn @ W_neigh + b_sage)
  gemm_k<1><<<nblk, 256, 0, stream>>>(h, Wst, hn, Wnt, bsage, h2, M);

  // out = relu(h2 @ W2 + b2)
  gemm_k<2><<<nblk, 256, 0, stream>>>(h2, W2t, nullptr, nullptr, b2, d_out, M);
}

// Round 7
// 296.103 us; speedup vs baseline: 1.0937x; 1.0937x over previous
//
#include <hip/hip_runtime.h>

// SAGEDense: h=relu(x@W1+b1); hn=mean_agg(h,src,dst); h2=relu(h@Ws+hn@Wn+b); out=relu(h2@W2+b2)
// GEMMs: M=100000, N=K=128, bf16 MFMA fp32-accum. GEMM2+GEMM3 fused (h2 stays in LDS).
// Aggregation: bin8 (fused degree-count + octant binning, block-reserved ranges)
// -> scan -> per-XCD fill -> register-accumulating gather.

typedef __bf16 bf16x8 __attribute__((ext_vector_type(8)));
typedef float f32x4 __attribute__((ext_vector_type(4)));

#define D 128

__device__ __forceinline__ unsigned short f2bf(float f){
  unsigned int u = __float_as_uint(f);
  u += 0x7FFF + ((u >> 16) & 1);           // RNE
  return (unsigned short)(u >> 16);
}
__device__ __forceinline__ float bf2f(unsigned int us){
  return __uint_as_float(us << 16);
}

// All 4 weights in one launch: 512 blocks = 4 x 128 k-rows; [k][n] fp32 -> [n][k] bf16
__global__ void prep_w_all(const float* __restrict__ Wa, const float* __restrict__ Wb,
                           const float* __restrict__ Wc, const float* __restrict__ Wd,
                           unsigned short* __restrict__ Ta, unsigned short* __restrict__ Tb,
                           unsigned short* __restrict__ Tc, unsigned short* __restrict__ Td){
  int which = blockIdx.x >> 7;
  int k = blockIdx.x & 127;
  int n = threadIdx.x;
  const float* W = (which == 0) ? Wa : (which == 1) ? Wb : (which == 2) ? Wc : Wd;
  unsigned short* T = (which == 0) ? Ta : (which == 1) ? Tb : (which == 2) ? Tc : Td;
  T[n * D + k] = f2bf(W[k * D + n]);
}

// ---------------- bin8: degree count + octant binning in ONE edge pass ----------------
// Block handles 4096 edges. Phase1: count per-octant in LDS + per-node degree atomics.
// Phase2: block reserves a contiguous range per octant (1 global atomic each) and
// re-reads its edges (L1/L2-hot, 32KB reuse distance), writing (src,dst) uint2 into
// block-private ranges -> every eoct cache line has ONE writer -> writes merge.
__launch_bounds__(256)
__global__ void bin8(const int* __restrict__ esrc, const int* __restrict__ edst,
                     int* __restrict__ cnt, int* __restrict__ ofill,
                     uint2* __restrict__ eoct, int E, int cap, float inv_octw){
  __shared__ int lcnt[8], lbase[8], lrank[8];
  const int t = threadIdx.x;
  if (t < 8) lcnt[t] = 0;
  __syncthreads();
  const int base = blockIdx.x * 4096;
  const int lim = min(base + 4096, E);
  for (int i = base + t; i < lim; i += 256){
    int d = edst[i];
    atomicAdd(&cnt[d], 1);
    int o = min((int)((float)d * inv_octw), 7);
    atomicAdd(&lcnt[o], 1);
  }
  __syncthreads();
  if (t < 8){ lbase[t] = atomicAdd(&ofill[t], lcnt[t]); lrank[t] = 0; }
  __syncthreads();
  for (int i = base + t; i < lim; i += 256){
    int s = esrc[i];
    int d = edst[i];
    int o = min((int)((float)d * inv_octw), 7);
    int r = atomicAdd(&lrank[o], 1);
    int p = lbase[o] + r;
    if (p < cap) eoct[(size_t)o * cap + p] = make_uint2((unsigned)s, (unsigned)d);
  }
}

// ---------------- multi-block exclusive scan of cnt -> rowptr & fillpos ----------------
__global__ void scan_a(const int* __restrict__ in, int* __restrict__ bsum, int N){
  __shared__ int red[256];
  int t = threadIdx.x;
  int i0 = blockIdx.x * 512 + t * 2;
  int s = 0;
  if (i0 < N)     s += in[i0];
  if (i0 + 1 < N) s += in[i0 + 1];
  red[t] = s;
  __syncthreads();
  #pragma unroll
  for (int d = 128; d > 0; d >>= 1){
    if (t < d) red[t] += red[t + d];
    __syncthreads();
  }
  if (t == 0) bsum[blockIdx.x] = red[0];
}

__global__ void scan_b(const int* __restrict__ bsum, int* __restrict__ boff, int nb){
  __shared__ int buf[256];
  int t = threadIdx.x;
  buf[t] = (t < nb) ? bsum[t] : 0;
  __syncthreads();
  #pragma unroll
  for (int d = 1; d < 256; d <<= 1){
    int v = (t >= d) ? buf[t - d] : 0;
    __syncthreads();
    buf[t] += v;
    __syncthreads();
  }
  if (t < nb) boff[t] = (t == 0) ? 0 : buf[t - 1];
}

__global__ void scan_c(const int* __restrict__ in, const int* __restrict__ boff,
                       int* __restrict__ rowptr, int* __restrict__ fillpos, int N){
  __shared__ int buf[256];
  int t = threadIdx.x;
  int i0 = blockIdx.x * 512 + t * 2;
  int c0 = (i0 < N)     ? in[i0]     : 0;
  int c1 = (i0 + 1 < N) ? in[i0 + 1] : 0;
  buf[t] = c0 + c1;
  __syncthreads();
  #pragma unroll
  for (int d = 1; d < 256; d <<= 1){
    int v = (t >= d) ? buf[t - d] : 0;
    __syncthreads();
    buf[t] += v;
    __syncthreads();
  }
  int excl = ((t == 0) ? 0 : buf[t - 1]) + boff[blockIdx.x];
  if (i0 < N)    { rowptr[i0]     = excl;      fillpos[i0]     = excl; }
  if (i0 + 1 < N){ rowptr[i0 + 1] = excl + c0; fillpos[i0 + 1] = excl + c0; }
  if (i0 + 1 == N - 1) rowptr[N] = excl + c0 + c1;
  if (i0 == N - 1)     rowptr[N] = excl + c0;
}

// ---------------- per-XCD CSR fill from octant lists ----------------
// blockIdx&7 = octant (round-robin -> pinned XCD). Each XCD streams only its own
// ~1.7MB list while keeping its ~800KB adj frontier L2-resident -> writes merge.
__launch_bounds__(256)
__global__ void fill_adj_oct(const uint2* __restrict__ eoct, const int* __restrict__ ofill,
                             int* __restrict__ fillpos, int* __restrict__ adj,
                             int cap, int nchunk){
  const int o = blockIdx.x & 7;
  const int chunk = blockIdx.x >> 3;
  const int n = min(ofill[o], cap);
  const uint2* lst = eoct + (size_t)o * cap;
  for (int i = chunk * 256 + (int)threadIdx.x; i < n; i += nchunk * 256){
    uint2 e = lst[i];
    int p = atomicAdd(&fillpos[e.y], 1);
    adj[p] = (int)e.x;
  }
}

// one wave per dst node; lane owns 4 bytes (2 bf16 dims); fp32 register accumulate
__global__ void gather_mean(const unsigned short* __restrict__ h,
                            const int* __restrict__ rowptr,
                            const int* __restrict__ adj,
                            unsigned short* __restrict__ hn, int N){
  int wid = (blockIdx.x * blockDim.x + threadIdx.x) >> 6;
  int lane = threadIdx.x & 63;
  if (wid >= N) return;
  int beg = rowptr[wid], end = rowptr[wid + 1];
  float a0 = 0.f, a1 = 0.f;
  int i = beg;
  for (; i + 3 < end; i += 4){
    int s0 = adj[i], s1 = adj[i + 1], s2 = adj[i + 2], s3 = adj[i + 3];
    unsigned p0 = *(const unsigned*)(h + (size_t)s0 * D + lane * 2);
    unsigned p1 = *(const unsigned*)(h + (size_t)s1 * D + lane * 2);
    unsigned p2 = *(const unsigned*)(h + (size_t)s2 * D + lane * 2);
    unsigned p3 = *(const unsigned*)(h + (size_t)s3 * D + lane * 2);
    a0 += bf2f(p0 & 0xffffu); a1 += bf2f(p0 >> 16);
    a0 += bf2f(p1 & 0xffffu); a1 += bf2f(p1 >> 16);
    a0 += bf2f(p2 & 0xffffu); a1 += bf2f(p2 >> 16);
    a0 += bf2f(p3 & 0xffffu); a1 += bf2f(p3 >> 16);
  }
  for (; i < end; i++){
    int s0 = adj[i];
    unsigned p0 = *(const unsigned*)(h + (size_t)s0 * D + lane * 2);
    a0 += bf2f(p0 & 0xffffu); a1 += bf2f(p0 >> 16);
  }
  float inv = 1.0f / fmaxf((float)(end - beg), 1.0f);
  unsigned o = (unsigned)f2bf(a0 * inv) | ((unsigned)f2bf(a1 * inv) << 16);
  *(unsigned*)(hn + (size_t)wid * D + lane * 2) = o;
}

// ---------------- GEMM building blocks ----------------
#define STAGE_BF16(A, dstLDS)                                              \
  _Pragma("unroll")                                                        \
  for (int i = 0; i < 8; i++){                                             \
    int idx = t + i * 256;                                                 \
    int row = idx >> 4;                                                    \
    int inb = (idx & 15) << 4;                                             \
    int g = rowBase + row; if (g >= M) g = M - 1;                          \
    uint4 v = *(const uint4*)((const char*)(A) + (size_t)g * 256 + inb);   \
    *(uint4*)((char*)(dstLDS) + row * 256 + (inb ^ ((row & 7) << 4))) = v; \
  }

// GEMM1: fp32 in -> bf16 h out
__launch_bounds__(256, 2)
__global__ void gemm1(const float* __restrict__ A,
                      const unsigned short* __restrict__ Wt,
                      const float* __restrict__ bias,
                      unsigned short* __restrict__ out, int M)
{
  __shared__ unsigned short As[128 * 128];
  __shared__ unsigned short Bs[128 * 128];
  const int t = threadIdx.x;
  const int lane = t & 63;
  const int wave = t >> 6;
  const int rowBase = blockIdx.x * 128;

  f32x4 zero = {0.f, 0.f, 0.f, 0.f};
  f32x4 acc[4][4];
  #pragma unroll
  for (int i = 0; i < 4; i++)
    #pragma unroll
    for (int j = 0; j < 4; j++) acc[i][j] = zero;

  // stage fp32 A -> bf16 LDS
  #pragma unroll
  for (int i = 0; i < 8; i++){
    int idx = t + i * 256;
    int row = idx >> 4;
    int inb = (idx & 15) << 4;
    int g = rowBase + row; if (g >= M) g = M - 1;
    const float* src = A + (size_t)g * D + (inb >> 1);
    float4 v0 = *(const float4*)src;
    float4 v1 = *(const float4*)(src + 4);
    uint4 o;
    o.x = (unsigned)f2bf(v0.x) | ((unsigned)f2bf(v0.y) << 16);
    o.y = (unsigned)f2bf(v0.z) | ((unsigned)f2bf(v0.w) << 16);
    o.z = (unsigned)f2bf(v1.x) | ((unsigned)f2bf(v1.y) << 16);
    o.w = (unsigned)f2bf(v1.z) | ((unsigned)f2bf(v1.w) << 16);
    *(uint4*)((char*)As + row * 256 + (inb ^ ((row & 7) << 4))) = o;
  }
  // stage W
  #pragma unroll
  for (int i = 0; i < 8; i++){
    int idx = t + i * 256;
    int row = idx >> 4;
    int inb = (idx & 15) << 4;
    uint4 v = *(const uint4*)((const char*)Wt + row * 256 + inb);
    *(uint4*)((char*)Bs + row * 256 + (inb ^ ((row & 7) << 4))) = v;
  }
  __syncthreads();

  const int wr = (wave >> 1) * 64;
  const int wc = (wave & 1) * 64;
  const int fr = lane & 15;
  const int kg = lane >> 4;

  #pragma unroll
  for (int ks = 0; ks < 4; ks++){
    int kb = ks * 64 + kg * 16;
    bf16x8 a[4], b[4];
    #pragma unroll
    for (int mi = 0; mi < 4; mi++){
      int row = wr + mi * 16 + fr;
      a[mi] = __builtin_bit_cast(bf16x8, *(const uint4*)((const char*)As + row * 256 + (kb ^ ((row & 7) << 4))));
    }
    #pragma unroll
    for (int ni = 0; ni < 4; ni++){
      int row = wc + ni * 16 + fr;
      b[ni] = __builtin_bit_cast(bf16x8, *(const uint4*)((const char*)Bs + row * 256 + (kb ^ ((row & 7) << 4))));
    }
    #pragma unroll
    for (int mi = 0; mi < 4; mi++)
      #pragma unroll
      for (int ni = 0; ni < 4; ni++)
        acc[mi][ni] = __builtin_amdgcn_mfma_f32_16x16x32_bf16(a[mi], b[ni], acc[mi][ni], 0, 0, 0);
  }

  #pragma unroll
  for (int ni = 0; ni < 4; ni++){
    int col = wc + ni * 16 + fr;
    float bv = bias[col];
    #pragma unroll
    for (int mi = 0; mi < 4; mi++)
      #pragma unroll
      for (int j = 0; j < 4; j++){
        int row = rowBase + wr + mi * 16 + kg * 4 + j;
        if (row < M)
          out[(size_t)row * D + col] = f2bf(fmaxf(acc[mi][ni][j] + bv, 0.0f));
      }
  }
}

// Fused SAGE combine + final layer:
// h2 = relu(h@Ws + hn@Wn + bsage)  [kept in LDS as bf16]
// out = relu(h2@W2 + b2)           [fp32]
__launch_bounds__(256, 2)
__global__ void gemm_fused(const unsigned short* __restrict__ h,
                           const unsigned short* __restrict__ Wst,
                           const unsigned short* __restrict__ hn,
                           const unsigned short* __restrict__ Wnt,
                           const unsigned short* __restrict__ W2t,
                           const float* __restrict__ bsage,
                           const float* __restrict__ b2,
                           float* __restrict__ out, int M)
{
  __shared__ unsigned short As[128 * 128];
  __shared__ unsigned short Bs[128 * 128];
  const int t = threadIdx.x;
  const int lane = t & 63;
  const int wave = t >> 6;
  const int rowBase = blockIdx.x * 128;

  const int wr = (wave >> 1) * 64;
  const int wc = (wave & 1) * 64;
  const int fr = lane & 15;
  const int kg = lane >> 4;

  f32x4 zero = {0.f, 0.f, 0.f, 0.f};
  f32x4 acc[4][4];
  #pragma unroll
  for (int i = 0; i < 4; i++)
    #pragma unroll
    for (int j = 0; j < 4; j++) acc[i][j] = zero;

  auto stage_w = [&](const unsigned short* W){
    #pragma unroll
    for (int i = 0; i < 8; i++){
      int idx = t + i * 256;
      int row = idx >> 4;
      int inb = (idx & 15) << 4;
      uint4 v = *(const uint4*)((const char*)W + row * 256 + inb);
      *(uint4*)((char*)Bs + row * 256 + (inb ^ ((row & 7) << 4))) = v;
    }
  };
  auto mma_pass = [&](){
    #pragma unroll
    for (int ks = 0; ks < 4; ks++){
      int kb = ks * 64 + kg * 16;
      bf16x8 a[4], b[4];
      #pragma unroll
      for (int mi = 0; mi < 4; mi++){
        int row = wr + mi * 16 + fr;
        a[mi] = __builtin_bit_cast(bf16x8, *(const uint4*)((const char*)As + row * 256 + (kb ^ ((row & 7) << 4))));
      }
      #pragma unroll
      for (int ni = 0; ni < 4; ni++){
        int row = wc + ni * 16 + fr;
        b[ni] = __builtin_bit_cast(bf16x8, *(const uint4*)((const char*)Bs + row * 256 + (kb ^ ((row & 7) << 4))));
      }
      #pragma unroll
      for (int mi = 0; mi < 4; mi++)
        #pragma unroll
        for (int ni = 0; ni < 4; ni++)
          acc[mi][ni] = __builtin_amdgcn_mfma_f32_16x16x32_bf16(a[mi], b[ni], acc[mi][ni], 0, 0, 0);
    }
  };

  // pass 1: h @ Wst
  STAGE_BF16(h, As);
  stage_w(Wst);
  __syncthreads();
  mma_pass();
  __syncthreads();

  // pass 2: + hn @ Wnt
  STAGE_BF16(hn, As);
  stage_w(Wnt);
  __syncthreads();
  mma_pass();
  __syncthreads();   // everyone done with As/Bs

  // h2 = relu(acc + bsage) -> As (bf16, swizzled); reset acc
  #pragma unroll
  for (int ni = 0; ni < 4; ni++){
    int col = wc + ni * 16 + fr;
    float bv = bsage[col];
    #pragma unroll
    for (int mi = 0; mi < 4; mi++)
      #pragma unroll
      for (int j = 0; j < 4; j++){
        int row = wr + mi * 16 + kg * 4 + j;
        unsigned short hv = f2bf(fmaxf(acc[mi][ni][j] + bv, 0.0f));
        *(unsigned short*)((char*)As + row * 256 + ((col * 2) ^ ((row & 7) << 4))) = hv;
        acc[mi][ni][j] = 0.f;
      }
  }
  stage_w(W2t);
  __syncthreads();

  // pass 3: h2 @ W2t
  mma_pass();

  #pragma unroll
  for (int ni = 0; ni < 4; ni++){
    int col = wc + ni * 16 + fr;
    float bv = b2[col];
    #pragma unroll
    for (int mi = 0; mi < 4; mi++)
      #pragma unroll
      for (int j = 0; j < 4; j++){
        int row = rowBase + wr + mi * 16 + kg * 4 + j;
        if (row < M)
          out[(size_t)row * D + col] = fmaxf(acc[mi][ni][j] + bv, 0.0f);
      }
  }
}

extern "C" void kernel_launch(void* const* d_in, const int* in_sizes, int n_in,
                              void* d_out, int out_size, void* d_ws, size_t ws_size,
                              hipStream_t stream)
{
  const float* x     = (const float*)d_in[0];
  const int*   esrc  = (const int*)d_in[1];
  const int*   edst  = (const int*)d_in[2];
  const float* W1    = (const float*)d_in[3];
  const float* b1    = (const float*)d_in[4];
  const float* Wself = (const float*)d_in[5];
  const float* Wneigh= (const float*)d_in[6];
  const float* bsage = (const float*)d_in[7];
  const float* W2    = (const float*)d_in[8];
  const float* b2    = (const float*)d_in[9];

  const int M = in_sizes[0] / D;   // 100000
  const int E = in_sizes[1];       // 1600000
  const int octw = (M + 7) / 8;
  const float inv_octw = 1.0f / (float)octw;
  const int cap = ((E / 8 + 16384 + 63) / 64) * 64;   // per-octant capacity

  // ---- workspace layout (~73 MB) ----
  char* ws = (char*)d_ws;
  unsigned short* W1t = (unsigned short*)(ws);
  unsigned short* Wst = (unsigned short*)(ws + 32768);
  unsigned short* Wnt = (unsigned short*)(ws + 65536);
  unsigned short* W2t = (unsigned short*)(ws + 98304);
  size_t hbytes = (size_t)M * D * 2;            // 25.6 MB each
  unsigned short* h   = (unsigned short*)(ws + 131072);
  unsigned short* hn  = (unsigned short*)(ws + 131072 + hbytes);
  char* p = ws + 131072 + 2 * hbytes;
  int* cnt     = (int*)p;                 p += (size_t)M * 4;
  int* ofill   = (int*)p;                 p += 256;      // adjacent to cnt (one memset)
  int* fillpos = (int*)p;                 p += (size_t)M * 4;
  int* rowptr  = (int*)p;                 p += (size_t)(M + 4) * 4;
  int* bsum    = (int*)p;                 p += 1024;
  int* boff    = (int*)p;                 p += 1024;
  uint2* eoct  = (uint2*)p;               p += (size_t)cap * 8 * 8;  // 13.9 MB
  int* adj     = (int*)p;                 // E * 4 = 6.4 MB

  const int nbScan = (M + 511) / 512;     // 196 <= 256

  prep_w_all<<<4 * D, D, 0, stream>>>(W1, Wself, Wneigh, W2, W1t, Wst, Wnt, W2t);
  hipMemsetAsync(cnt, 0, (size_t)M * 4 + 256, stream);   // cnt + ofill

  int nblk = (M + 127) / 128;

  // h = relu(x @ W1 + b1)
  gemm1<<<nblk, 256, 0, stream>>>(x, W1t, b1, h, M);

  // degree count + octant binning (single edge pass)
  bin8<<<(E + 4095) / 4096, 256, 0, stream>>>(esrc, edst, cnt, ofill, eoct, E, cap, inv_octw);

  // rowptr/fillpos = exclusive scan of cnt
  scan_a<<<nbScan, 256, 0, stream>>>(cnt, bsum, M);
  scan_b<<<1, 256, 0, stream>>>(bsum, boff, nbScan);
  scan_c<<<nbScan, 256, 0, stream>>>(cnt, boff, rowptr, fillpos, M);

  // per-XCD CSR fill
  fill_adj_oct<<<8 * 96, 256, 0, stream>>>(eoct, ofill, fillpos, adj, cap, 96);

  // hn = mean over neighbors (bf16)
  gather_mean<<<(M * 64 + 255) / 256, 256, 0, stream>>>(h, rowptr, adj, hn, M);

  // out = relu( relu(h@Ws + hn@Wn + bsage) @ W2 + b2 )
  gemm_fused<<<nblk, 256, 0, stream>>>(h, Wst, hn, Wnt, W2t, bsage, b2, (float*)d_out, M);
}